// Round 8
// baseline (147.736 us; speedup 1.0000x reference)
//
#include <hip/hip_runtime.h>
#include <hip/hip_bf16.h>
#include <stdint.h>

#define B_   4
#define N_   10000
#define K_   16
#define D_   256
#define OUT_ 256
#define KDIM 512          // 2*D
#define M_   (B_ * N_)    // 40000
#define CW   32           // cols per gather chunk (64 B rows)
#define NCH  8            // number of chunks (one per XCD)
#define CHUNK_ELEMS ((size_t)N_ * B_ * CW)   // ushorts per chunk = 1,280,000

typedef __attribute__((ext_vector_type(8))) short          short8;    // MFMA frag
typedef __attribute__((ext_vector_type(8))) unsigned short ushort8;
typedef __attribute__((ext_vector_type(4))) float          f32x4;
typedef __attribute__((ext_vector_type(4))) unsigned short ushort4_t;

__device__ inline unsigned short f2bf(float f) {
    __hip_bfloat16 h = __float2bfloat16(f);
    return *reinterpret_cast<unsigned short*>(&h);
}
__device__ inline float bf2f(unsigned short u) {
    unsigned int v = ((unsigned int)u) << 16;
    return __builtin_bit_cast(float, v);
}

// ---------------------------------------------------------------------------
// Kernel 1 (prep): blocks 0..4999 : x fp32 (B,N,D) -> xc bf16 chunk-major
//   (8 chunks)[n][b][32 cols]; chunk = 2.56 MB (fits one XCD L2).
// blocks 5000..5127 : W fp32 -> Wb bf16 (B^T layout for the GEMM).
// ---------------------------------------------------------------------------
__global__ __launch_bounds__(256) void prep(const float* __restrict__ x,
                                            const float* __restrict__ W,
                                            unsigned short* __restrict__ xc,
                                            unsigned short* __restrict__ Wb) {
    const int t = threadIdx.x;
    if (blockIdx.x < 5000) {
        const int n  = blockIdx.x * 2 + (t >> 7);      // node
        const int b  = (t >> 5) & 3;                   // batch
        const int c0 = (t & 31) * 8;                   // col base (multiple of 8)
        const float4* xr = (const float4*)(x + ((size_t)b * N_ + n) * D_ + c0);
        float4 v0 = xr[0];
        float4 v1 = xr[1];
        ushort8 s;
        s[0] = f2bf(v0.x); s[1] = f2bf(v0.y); s[2] = f2bf(v0.z); s[3] = f2bf(v0.w);
        s[4] = f2bf(v1.x); s[5] = f2bf(v1.y); s[6] = f2bf(v1.z); s[7] = f2bf(v1.w);
        const int ch  = c0 >> 5;          // chunk 0..7
        const int col = c0 & 31;          // 0,8,16,24
        *(ushort8*)(xc + (size_t)ch * CHUNK_ELEMS + ((size_t)n * B_ + b) * CW + col) = s;
    } else {
        int g = (blockIdx.x - 5000) * 256 + t;         // 0..32767, 4 elems each
        float4 v = ((const float4*)W)[g];
        ushort4_t s;
        s.x = f2bf(v.x); s.y = f2bf(v.y); s.z = f2bf(v.z); s.w = f2bf(v.w);
        ((ushort4_t*)Wb)[g] = s;
    }
}

// ---------------------------------------------------------------------------
// Kernel 2 (gather_agg): chunk c = blockIdx & 7 -> consecutive blocks
// round-robin XCDs, so each XCD's random gathers stay inside its own
// 2.56-MB L2-resident chunk. Block: 8 nodes x 4 batches = 32 tasks; 8 lanes
// per task; 16 independent 8-B gather loads per thread (deep MLP).
// Writes hagg: m-row-major M x 256 bf16, hagg[b*N+n][c*32 .. +32].
// ---------------------------------------------------------------------------
__global__ __launch_bounds__(256) void gather_agg(const unsigned short* __restrict__ xc,
                                                  const int*            __restrict__ neigh,
                                                  unsigned short*       __restrict__ hagg) {
    const int c   = blockIdx.x & 7;
    const int g   = blockIdx.x >> 3;
    const int n0  = g * 8;
    const int tid = threadIdx.x;

    __shared__ int   idx_s[8 * K_];
    __shared__ float inv_s[8];

    if (tid < 8 * K_) idx_s[tid] = neigh[n0 * K_ + tid];
    __syncthreads();
    if (tid < 8) {
        int cnt = 0;
#pragma unroll
        for (int k = 0; k < K_; ++k) cnt += idx_s[tid * K_ + k] >= 0 ? 1 : 0;
        inv_s[tid] = 1.0f / (float)(cnt > 1 ? cnt : 1);
    }
    __syncthreads();

    const int q  = tid & 7;          // 4-col group within chunk
    const int tl = tid >> 3;         // task 0..31
    const int ns = tl >> 2;          // node_sub 0..7
    const int b  = tl & 3;           // batch

    const unsigned short* xcc = xc + (size_t)c * CHUNK_ELEMS;

    int jj[K_];
#pragma unroll
    for (int k = 0; k < K_; ++k) jj[k] = idx_s[ns * K_ + k];

    ushort4_t vv[K_];
#pragma unroll
    for (int k = 0; k < K_; ++k) {
        const int jc = jj[k] >= 0 ? jj[k] : 0;
        vv[k] = *(const ushort4_t*)(xcc + ((size_t)jc * B_ + b) * CW + q * 4);
    }

    float a0 = 0.f, a1 = 0.f, a2 = 0.f, a3 = 0.f;
#pragma unroll
    for (int k = 0; k < K_; ++k) {
        const float m = jj[k] >= 0 ? 1.f : 0.f;
        a0 += bf2f(vv[k].x) * m;
        a1 += bf2f(vv[k].y) * m;
        a2 += bf2f(vv[k].z) * m;
        a3 += bf2f(vv[k].w) * m;
    }
    const float inv = inv_s[ns];

    ushort4_t s;
    s.x = f2bf(a0 * inv); s.y = f2bf(a1 * inv);
    s.z = f2bf(a2 * inv); s.w = f2bf(a3 * inv);
    *(ushort4_t*)(hagg + ((size_t)b * N_ + n0 + ns) * D_ + c * CW + q * 4) = s;
}

// ---------------------------------------------------------------------------
// Kernel 3 (gemm_bt4): out[m,o] = relu( [self|agg] . Wb[o,:] + bias[o] )
// 128x128 tile, BK=64 (two BK=32 sub-chunks per barrier pair): grid (313,2),
// 4 waves. Waves 0/1 stage A sub 0/1 (8 chunks each, per-lane sources from
// xc/hagg as in bt3); waves 2/3 stage B sub 0/1 from L2-resident Wb.
// 8 K-iters (vs 16), 32 MFMA/wave per barrier pair, 24 KB staged / 2.1 MFLOP
// = 87 FLOP/B from L2 (off the 34.5 TB/s L2 roofline). LDS 32 KB.
// Tail block (rows >= M_): staging rows clamped, stores masked.
// ---------------------------------------------------------------------------
__global__ __launch_bounds__(256) void gemm_bt4(const unsigned short* __restrict__ xc,
                                                const unsigned short* __restrict__ hagg,
                                                const unsigned short* __restrict__ Bm,  // Wb
                                                const float* __restrict__ bias,
                                                float* __restrict__ out) {
    __shared__ unsigned short As[2 * 128 * 32];   // 16 KB: [sub][row 0..127][32]
    __shared__ unsigned short Bs[2 * 128 * 32];   // 16 KB

    const int tid    = threadIdx.x;
    const int w      = tid >> 6;
    const int lane   = tid & 63;
    const int tile_m = blockIdx.x * 128;
    const int nt     = blockIdx.y;                // col tile: cols nt*128..+128
    const int wm     = w & 1;
    const int wn     = w >> 1;
    const int q      = lane >> 4;
    const int r16    = lane & 15;

    const int crow = lane >> 2;        // 0..15: row within a 16-row chunk
    const int kofs = (lane & 3) * 8;   // ushort offset within BK=32

    // Per-lane source pointers for the 8 row-chunks (computed once).
    const unsigned short* ps[8];   // self (xc): + kidx*CHUNK_ELEMS
    const unsigned short* pa[8];   // agg (hagg): + (kks-256)
    const unsigned short* pb[8];   // B (Wb): + kks
#pragma unroll
    for (int c = 0; c < 8; ++c) {
        int m = tile_m + c * 16 + crow;
        if (m > M_ - 1) m = M_ - 1;                 // clamp tail staging
        const int b = (m >= N_) + (m >= 2 * N_) + (m >= 3 * N_);
        const int n = m - b * N_;
        ps[c] = xc + ((size_t)n * B_ + b) * CW + kofs;
        pa[c] = hagg + (size_t)m * D_ + kofs;
        pb[c] = Bm + (size_t)(nt * 128 + c * 16 + crow) * KDIM + kofs;
    }

    f32x4 acc[4][4] = {};

    for (int it = 0; it < 8; ++it) {
        const int kk = it * 64;
        if (w < 2) {
            const int kks = kk + w * 32;            // sub = w
#pragma unroll
            for (int c = 0; c < 8; ++c) {
                const unsigned short* ga = (kks < D_)
                    ? ps[c] + (size_t)(kks >> 5) * CHUNK_ELEMS
                    : pa[c] + (kks - D_);
                __builtin_amdgcn_global_load_lds(
                    (const __attribute__((address_space(1))) void*)ga,
                    (__attribute__((address_space(3))) void*)(As + w * 4096 + c * 512),
                    16, 0, 0);
            }
        } else {
            const int kks = kk + (w - 2) * 32;      // sub = w-2
#pragma unroll
            for (int c = 0; c < 8; ++c) {
                const unsigned short* gb = pb[c] + kks;
                __builtin_amdgcn_global_load_lds(
                    (const __attribute__((address_space(1))) void*)gb,
                    (__attribute__((address_space(3))) void*)(Bs + (w - 2) * 4096 + c * 512),
                    16, 0, 0);
            }
        }
        __syncthreads();

#pragma unroll
        for (int sub = 0; sub < 2; ++sub) {
            short8 a[4], bf[4];
#pragma unroll
            for (int i = 0; i < 4; ++i)
                a[i] = *(const short8*)(As + sub * 4096 + (wm * 64 + i * 16 + r16) * 32 + q * 8);
#pragma unroll
            for (int j = 0; j < 4; ++j)
                bf[j] = *(const short8*)(Bs + sub * 4096 + (wn * 64 + j * 16 + r16) * 32 + q * 8);

#pragma unroll
            for (int i = 0; i < 4; ++i)
#pragma unroll
                for (int j = 0; j < 4; ++j)
                    acc[i][j] = __builtin_amdgcn_mfma_f32_16x16x32_bf16(a[i], bf[j], acc[i][j], 0, 0, 0);
        }
        __syncthreads();
    }

    // Epilogue: bias + ReLU; mask rows past M_ (tail block only).
    float bj[4];
#pragma unroll
    for (int j = 0; j < 4; ++j)
        bj[j] = bias[nt * 128 + wn * 64 + j * 16 + r16];

#pragma unroll
    for (int i = 0; i < 4; ++i) {
#pragma unroll
        for (int reg = 0; reg < 4; ++reg) {
            const int m = tile_m + wm * 64 + i * 16 + q * 4 + reg;
            if (m < M_) {
                float* orow = out + (size_t)m * OUT_ + nt * 128 + wn * 64;
#pragma unroll
                for (int j = 0; j < 4; ++j) {
                    float v = acc[i][j][reg] + bj[j];
                    orow[j * 16 + r16] = v > 0.f ? v : 0.f;
                }
            }
        }
    }
}

// ---------------------------------------------------------------------------
extern "C" void kernel_launch(void* const* d_in, const int* in_sizes, int n_in,
                              void* d_out, int out_size, void* d_ws, size_t ws_size,
                              hipStream_t stream) {
    const float* x     = (const float*)d_in[0];   // (4, 10000, 256) fp32
    const int*   neigh = (const int*)d_in[1];     // (10000, 16) int32
    const float* W     = (const float*)d_in[2];   // (256, 512) fp32
    const float* bias  = (const float*)d_in[3];   // (256,) fp32
    float*       out   = (float*)d_out;           // (4, 10000, 256) fp32

    unsigned short* Wb   = (unsigned short*)d_ws;         // 256*512 bf16 = 0.26 MB
    unsigned short* xc   = Wb + OUT_ * KDIM;              // 8 x 2.56 MB = 20.48 MB
    unsigned short* hagg = xc + NCH * CHUNK_ELEMS;        // 40000*256 bf16 = 20.48 MB

    prep<<<5000 + 128, 256, 0, stream>>>(x, W, xc, Wb);
    gather_agg<<<(N_ / 8) * NCH, 256, 0, stream>>>(xc, neigh, hagg);
    gemm_bt4<<<dim3((M_ + 127) / 128, OUT_ / 128), 256, 0, stream>>>(xc, hagg, Wb, bias, out);
}

// Round 9
// 132.112 us; speedup vs baseline: 1.1183x; 1.1183x over previous
//
#include <hip/hip_runtime.h>
#include <hip/hip_bf16.h>
#include <stdint.h>

#define B_   4
#define N_   10000
#define K_   16
#define D_   256
#define OUT_ 256
#define KDIM 512          // 2*D
#define M_   (B_ * N_)    // 40000
#define CW   32           // cols per gather chunk (64 B rows)
#define NCH  8            // number of chunks (one per XCD)
#define CHUNK_ELEMS ((size_t)N_ * B_ * CW)   // ushorts per chunk = 1,280,000

typedef __attribute__((ext_vector_type(8))) short          short8;    // MFMA frag
typedef __attribute__((ext_vector_type(8))) unsigned short ushort8;
typedef __attribute__((ext_vector_type(4))) float          f32x4;
typedef __attribute__((ext_vector_type(4))) unsigned short ushort4_t;

__device__ inline unsigned short f2bf(float f) {
    __hip_bfloat16 h = __float2bfloat16(f);
    return *reinterpret_cast<unsigned short*>(&h);
}
__device__ inline float bf2f(unsigned short u) {
    unsigned int v = ((unsigned int)u) << 16;
    return __builtin_bit_cast(float, v);
}

// ---------------------------------------------------------------------------
// Kernel 1 (prep): blocks 0..4999 : x fp32 (B,N,D) -> xc bf16 chunk-major
//   (8 chunks)[n][b][32 cols]; chunk = 2.56 MB (fits one XCD L2).
// blocks 5000..5127 : W fp32 -> Wb bf16 (B^T layout for the GEMM).
// ---------------------------------------------------------------------------
__global__ __launch_bounds__(256) void prep(const float* __restrict__ x,
                                            const float* __restrict__ W,
                                            unsigned short* __restrict__ xc,
                                            unsigned short* __restrict__ Wb) {
    const int t = threadIdx.x;
    if (blockIdx.x < 5000) {
        const int n  = blockIdx.x * 2 + (t >> 7);      // node
        const int b  = (t >> 5) & 3;                   // batch
        const int c0 = (t & 31) * 8;                   // col base (multiple of 8)
        const float4* xr = (const float4*)(x + ((size_t)b * N_ + n) * D_ + c0);
        float4 v0 = xr[0];
        float4 v1 = xr[1];
        ushort8 s;
        s[0] = f2bf(v0.x); s[1] = f2bf(v0.y); s[2] = f2bf(v0.z); s[3] = f2bf(v0.w);
        s[4] = f2bf(v1.x); s[5] = f2bf(v1.y); s[6] = f2bf(v1.z); s[7] = f2bf(v1.w);
        const int ch  = c0 >> 5;          // chunk 0..7
        const int col = c0 & 31;          // 0,8,16,24
        *(ushort8*)(xc + (size_t)ch * CHUNK_ELEMS + ((size_t)n * B_ + b) * CW + col) = s;
    } else {
        int g = (blockIdx.x - 5000) * 256 + t;         // 0..32767, 4 elems each
        float4 v = ((const float4*)W)[g];
        ushort4_t s;
        s.x = f2bf(v.x); s.y = f2bf(v.y); s.z = f2bf(v.z); s.w = f2bf(v.w);
        ((ushort4_t*)Wb)[g] = s;
    }
}

// ---------------------------------------------------------------------------
// Kernel 2 (gather_agg2): chunk c = blockIdx & 7 -> consecutive blocks
// round-robin XCDs; each XCD's random gathers stay inside its own 2.56-MB
// L2-resident chunk. Block: 16 nodes x 4 batches = 64 tasks; 4 lanes per
// task, 16-B loads (halves load/write instr count vs 8-B variant).
// 16 independent gather loads per thread (deep MLP).
// Writes hagg: m-row-major M x 256 bf16, hagg[b*N+n][c*32 .. +32].
// ---------------------------------------------------------------------------
__global__ __launch_bounds__(256) void gather_agg2(const unsigned short* __restrict__ xc,
                                                   const int*            __restrict__ neigh,
                                                   unsigned short*       __restrict__ hagg) {
    const int c   = blockIdx.x & 7;
    const int g   = blockIdx.x >> 3;
    const int n0  = g * 16;
    const int tid = threadIdx.x;

    __shared__ int   idx_s[16 * K_];   // 256 ints
    __shared__ float inv_s[16];

    idx_s[tid] = neigh[n0 * K_ + tid];
    __syncthreads();
    if (tid < 16) {
        int cnt = 0;
#pragma unroll
        for (int k = 0; k < K_; ++k) cnt += idx_s[tid * K_ + k] >= 0 ? 1 : 0;
        inv_s[tid] = 1.0f / (float)(cnt > 1 ? cnt : 1);
    }
    __syncthreads();

    const int q  = tid & 3;          // 8-ushort col group within chunk
    const int tl = tid >> 2;         // task 0..63
    const int ns = tl >> 2;          // node_sub 0..15
    const int b  = tl & 3;           // batch

    const unsigned short* xcc = xc + (size_t)c * CHUNK_ELEMS;

    int jj[K_];
#pragma unroll
    for (int k = 0; k < K_; ++k) jj[k] = idx_s[ns * K_ + k];

    // 16 independent 16-B gather loads
    ushort8 vv[K_];
#pragma unroll
    for (int k = 0; k < K_; ++k) {
        const int jc = jj[k] >= 0 ? jj[k] : 0;
        vv[k] = *(const ushort8*)(xcc + ((size_t)jc * B_ + b) * CW + q * 8);
    }

    float acc[8] = {0.f, 0.f, 0.f, 0.f, 0.f, 0.f, 0.f, 0.f};
#pragma unroll
    for (int k = 0; k < K_; ++k) {
        const float m = jj[k] >= 0 ? 1.f : 0.f;
#pragma unroll
        for (int e = 0; e < 8; ++e) acc[e] += bf2f(vv[k][e]) * m;
    }
    const float inv = inv_s[ns];

    ushort8 s;
#pragma unroll
    for (int e = 0; e < 8; ++e) s[e] = f2bf(acc[e] * inv);
    *(ushort8*)(hagg + ((size_t)b * N_ + n0 + ns) * D_ + c * CW + q * 8) = s;
}

// ---------------------------------------------------------------------------
// Kernel 3 (gemm_bt3): out[m,o] = relu( [self|agg] . Wb[o,:] + bias[o] )
// Proven round-7 structure, unchanged: 64x256 tile, 625 blocks, BK=32,
// global_load_lds(16B) with per-lane scattered A sources from xc/hagg.
// ---------------------------------------------------------------------------
__global__ __launch_bounds__(256) void gemm_bt3(const unsigned short* __restrict__ xc,
                                                const unsigned short* __restrict__ hagg,
                                                const unsigned short* __restrict__ Bm,  // Wb
                                                const float* __restrict__ bias,
                                                float* __restrict__ out) {
    __shared__ unsigned short As[64 * 32];    //  4 KB
    __shared__ unsigned short Bs[256 * 32];   // 16 KB

    const int tid    = threadIdx.x;
    const int w      = tid >> 6;
    const int lane   = tid & 63;
    const int tile_m = blockIdx.x * 64;
    const int q      = lane >> 4;
    const int r16    = lane & 15;

    const int crow = lane >> 2;        // 0..15: row within a 16-row chunk
    const int kofs = (lane & 3) * 8;   // ushort offset within BK=32

    const unsigned short* ps[4];
    const unsigned short* pa[4];
#pragma unroll
    for (int c = 0; c < 4; ++c) {
        const int m  = tile_m + c * 16 + crow;
        const int b  = (m >= N_) + (m >= 2 * N_) + (m >= 3 * N_);
        const int n  = m - b * N_;
        ps[c] = xc + ((size_t)n * B_ + b) * CW + kofs;     // + kidx*CHUNK_ELEMS
        pa[c] = hagg + (size_t)m * D_ + kofs;              // + (kk-256)
    }

    f32x4 acc[4][4] = {};

    for (int kk = 0; kk < KDIM; kk += 32) {
        const int kidx = kk >> 5;
#pragma unroll
        for (int t = 0; t < 5; ++t) {
            const int c = w * 5 + t;               // chunk 0..19
            if (c < 4) {                           // A chunks
                const unsigned short* ga = (kk < D_)
                    ? ps[c] + (size_t)kidx * CHUNK_ELEMS
                    : pa[c] + (kk - D_);
                __builtin_amdgcn_global_load_lds(
                    (const __attribute__((address_space(1))) void*)ga,
                    (__attribute__((address_space(3))) void*)(As + c * 512),
                    16, 0, 0);
            } else {                               // B chunks
                const int row = (c - 4) * 16 + crow;
                const unsigned short* gb = Bm + (size_t)row * KDIM + kk + kofs;
                __builtin_amdgcn_global_load_lds(
                    (const __attribute__((address_space(1))) void*)gb,
                    (__attribute__((address_space(3))) void*)(Bs + (c - 4) * 512),
                    16, 0, 0);
            }
        }
        __syncthreads();

        short8 a[4], bf[4];
#pragma unroll
        for (int i = 0; i < 4; ++i)
            a[i] = *(const short8*)(As + (i * 16 + r16) * 32 + q * 8);
#pragma unroll
        for (int j = 0; j < 4; ++j)
            bf[j] = *(const short8*)(Bs + (w * 64 + j * 16 + r16) * 32 + q * 8);

#pragma unroll
        for (int i = 0; i < 4; ++i)
#pragma unroll
            for (int j = 0; j < 4; ++j)
                acc[i][j] = __builtin_amdgcn_mfma_f32_16x16x32_bf16(a[i], bf[j], acc[i][j], 0, 0, 0);

        __syncthreads();
    }

    float bj[4];
#pragma unroll
    for (int j = 0; j < 4; ++j)
        bj[j] = bias[w * 64 + j * 16 + r16];

#pragma unroll
    for (int i = 0; i < 4; ++i) {
#pragma unroll
        for (int reg = 0; reg < 4; ++reg) {
            const int m = tile_m + i * 16 + q * 4 + reg;
            float* orow = out + (size_t)m * OUT_ + w * 64;
#pragma unroll
            for (int j = 0; j < 4; ++j) {
                float v = acc[i][j][reg] + bj[j];
                orow[j * 16 + r16] = v > 0.f ? v : 0.f;
            }
        }
    }
}

// ---------------------------------------------------------------------------
extern "C" void kernel_launch(void* const* d_in, const int* in_sizes, int n_in,
                              void* d_out, int out_size, void* d_ws, size_t ws_size,
                              hipStream_t stream) {
    const float* x     = (const float*)d_in[0];   // (4, 10000, 256) fp32
    const int*   neigh = (const int*)d_in[1];     // (10000, 16) int32
    const float* W     = (const float*)d_in[2];   // (256, 512) fp32
    const float* bias  = (const float*)d_in[3];   // (256,) fp32
    float*       out   = (float*)d_out;           // (4, 10000, 256) fp32

    unsigned short* Wb   = (unsigned short*)d_ws;         // 256*512 bf16 = 0.26 MB
    unsigned short* xc   = Wb + OUT_ * KDIM;              // 8 x 2.56 MB = 20.48 MB
    unsigned short* hagg = xc + NCH * CHUNK_ELEMS;        // 40000*256 bf16 = 20.48 MB

    prep<<<5000 + 128, 256, 0, stream>>>(x, W, xc, Wb);
    gather_agg2<<<(N_ / 16) * NCH, 256, 0, stream>>>(xc, neigh, hagg);
    gemm_bt3<<<M_ / 64, 256, 0, stream>>>(xc, hagg, Wb, bias, out);
}